// Round 12
// baseline (196.173 us; speedup 1.0000x reference)
//
#include <hip/hip_runtime.h>

constexpr int NB    = 8;     // batches
constexpr int NN    = 256;   // sequence length
constexpr int F0    = 512;
constexpr int F1    = 256;
constexpr int F2    = 128;
constexpr int ROWS  = NB * NN;   // 2048
constexpr int KMAX  = 30;
constexpr float INF = 1e30f;

// ---------------- fp32 GEMM: C = act(A @ B + bias), 64x64 tile, BK=16 ----------
// Upgraded from 64x32/8-out to the corr_dist/mp_mm-proven 64x64/16-out tile:
// halves LDS traffic and barriers per FLOP. Per-output k-order unchanged
// (k0 ascending, kk ascending) -> bit-identical results.
__global__ __launch_bounds__(256) void gemm_bias_act(
    const float* __restrict__ A, const float* __restrict__ B,
    const float* __restrict__ bias, float* __restrict__ C,
    int M, int Ncols, int K, int relu)
{
  __shared__ float As[16][64];   // [k][m]
  __shared__ float Bs[16][64];   // [k][n]
  const int tid = threadIdx.x;
  const int tx = tid & 15;       // col group (4 cols)
  const int ty = tid >> 4;       // row group (4 rows)
  const int rowBase = blockIdx.y * 64;
  const int colBase = blockIdx.x * 64;
  float acc[4][4] = {};
  for (int k0 = 0; k0 < K; k0 += 16) {
    {
      const int r  = tid >> 2;
      const int kq = (tid & 3) << 2;
      const float4 av = *(const float4*)(A + (size_t)(rowBase + r) * K + (k0 + kq));
      As[kq+0][r] = av.x; As[kq+1][r] = av.y; As[kq+2][r] = av.z; As[kq+3][r] = av.w;
      const int kr = tid >> 4;
      const int c4 = (tid & 15) << 2;
      const float4 bv = *(const float4*)(B + (size_t)(k0 + kr) * Ncols + (colBase + c4));
      Bs[kr][c4+0] = bv.x; Bs[kr][c4+1] = bv.y; Bs[kr][c4+2] = bv.z; Bs[kr][c4+3] = bv.w;
    }
    __syncthreads();
    #pragma unroll
    for (int kk = 0; kk < 16; kk++) {
      const float4 a = *(const float4*)&As[kk][ty*4];
      const float4 bq = *(const float4*)&Bs[kk][tx*4];
      const float ar[4] = {a.x, a.y, a.z, a.w};
      const float br[4] = {bq.x, bq.y, bq.z, bq.w};
      #pragma unroll
      for (int i = 0; i < 4; i++)
        #pragma unroll
        for (int j = 0; j < 4; j++)
          acc[i][j] += ar[i] * br[j];
    }
    __syncthreads();
  }
  #pragma unroll
  for (int i = 0; i < 4; i++) {
    const int rr = rowBase + ty*4 + i;
    #pragma unroll
    for (int j = 0; j < 4; j++) {
      const int cc = colBase + tx*4 + j;
      float v = acc[i][j] + bias[cc];
      if (relu) v = fmaxf(v, 0.0f);
      C[(size_t)rr * Ncols + cc] = v;
    }
  }
}

// ---------------- D[b,n,m] = 0.5*(1 - (z_n.z_m)/sqrt(max(|z_n|^2|z_m|^2,1e-8)))
// Row/col norms accumulated in registers from the same LDS fragments.
__global__ __launch_bounds__(256) void corr_dist(
    const float* __restrict__ z, float* __restrict__ D)
{
  const int b = blockIdx.z;
  const float* zb = z + (size_t)b * NN * F2;
  __shared__ float As[16][64];  // [k][row]
  __shared__ float Bs[16][64];  // [k][col]
  const int tid = threadIdx.x;
  const int tx = tid & 15;
  const int ty = tid >> 4;
  const int rowBase = blockIdx.y * 64;
  const int colBase = blockIdx.x * 64;
  float acc[4][4] = {};
  float nsr[4] = {}, nsc[4] = {};
  for (int k0 = 0; k0 < F2; k0 += 16) {
    {
      const int r  = tid >> 2;
      const int kq = (tid & 3) << 2;
      const float4 av = *(const float4*)(zb + (size_t)(rowBase + r) * F2 + (k0 + kq));
      As[kq+0][r] = av.x; As[kq+1][r] = av.y; As[kq+2][r] = av.z; As[kq+3][r] = av.w;
      const float4 bv = *(const float4*)(zb + (size_t)(colBase + r) * F2 + (k0 + kq));
      Bs[kq+0][r] = bv.x; Bs[kq+1][r] = bv.y; Bs[kq+2][r] = bv.z; Bs[kq+3][r] = bv.w;
    }
    __syncthreads();
    #pragma unroll
    for (int kk = 0; kk < 16; kk++) {
      const float4 a = *(const float4*)&As[kk][ty*4];
      const float4 bq = *(const float4*)&Bs[kk][tx*4];
      const float ar[4] = {a.x, a.y, a.z, a.w};
      const float br[4] = {bq.x, bq.y, bq.z, bq.w};
      #pragma unroll
      for (int i = 0; i < 4; i++) { nsr[i] += ar[i]*ar[i]; nsc[i] += br[i]*br[i]; }
      #pragma unroll
      for (int i = 0; i < 4; i++)
        #pragma unroll
        for (int j = 0; j < 4; j++)
          acc[i][j] += ar[i] * br[j];
    }
    __syncthreads();
  }
  float* Db = D + (size_t)b * NN * NN;
  #pragma unroll
  for (int i = 0; i < 4; i++) {
    const int rr = rowBase + ty*4 + i;
    #pragma unroll
    for (int j = 0; j < 4; j++) {
      const int cc = colBase + tx*4 + j;
      const float denom = sqrtf(fmaxf(nsr[i] * nsc[j], 1e-8f));
      Db[(size_t)rr * NN + cc] = 0.5f * (1.0f - acc[i][j] / denom);
    }
  }
}

// ---------------- fused row scan + slab column scan ----------------------------
// Block = (batch, 32-row slab): row-scan 32 rows into a 64 KB LDS slab, then
// column-scan the slab in place; emit S (slab-local) + aux (slab totals).
__global__ __launch_bounds__(256) void scan_slab(
    const float* __restrict__ D, double* __restrict__ S, double* __restrict__ aux)
{
  const int s = blockIdx.x & 7;
  const int b = blockIdx.x >> 3;
  const int tid = threadIdx.x;
  const int wave = tid >> 6, lane = tid & 63;
  __shared__ double sd[32][NN];    // 64 KB
  for (int t = 0; t < 8; t++) {
    const int rl = wave * 8 + t;
    const float4 dv = *(const float4*)(D + (size_t)(b * NN + s * 32 + rl) * NN + lane * 4);
    double d0 = dv.x, d1 = dv.y, d2 = dv.z, d3 = dv.w;
    double p0 = d0, p1 = p0 + d1, p2 = p1 + d2, p3 = p2 + d3;
    double tt = p3;
    #pragma unroll
    for (int d = 1; d < 64; d <<= 1) {
      double u = __shfl_up(tt, d);
      if (lane >= d) tt += u;
    }
    const double off = tt - p3;
    sd[rl][lane*4+0] = off + p0; sd[rl][lane*4+1] = off + p1;
    sd[rl][lane*4+2] = off + p2; sd[rl][lane*4+3] = off + p3;
  }
  __syncthreads();
  const int j = tid;
  double* Sp = S + (size_t)b * NN * NN + (size_t)(s * 32) * NN + j;
  double sum = 0.0;
  for (int r = 0; r < 32; r += 8) {
    double v0 = sd[r+0][j], v1 = sd[r+1][j], v2 = sd[r+2][j], v3 = sd[r+3][j];
    double v4 = sd[r+4][j], v5 = sd[r+5][j], v6 = sd[r+6][j], v7 = sd[r+7][j];
    v0 += sum; v1 += v0; v2 += v1; v3 += v2; v4 += v3; v5 += v4; v6 += v5; v7 += v6;
    Sp[(size_t)(r+0)*NN] = v0; Sp[(size_t)(r+1)*NN] = v1;
    Sp[(size_t)(r+2)*NN] = v2; Sp[(size_t)(r+3)*NN] = v3;
    Sp[(size_t)(r+4)*NN] = v4; Sp[(size_t)(r+5)*NN] = v5;
    Sp[(size_t)(r+6)*NN] = v6; Sp[(size_t)(r+7)*NN] = v7;
    sum = v7;
  }
  aux[((size_t)b * 8 + s) * NN + j] = sum;
}

// ---------------- Ds -> A (shifted), C0 -> Cstk[0], out init -------------------
// S holds slab-local scans; cross-slab column offsets P (exclusive prefix of
// aux) are built in LDS and added on the fly: S_full[r][j] = S[r][j]+P[r>>5][j].
__global__ __launch_bounds__(256) void ds_mat(
    const double* __restrict__ S, const double* __restrict__ aux,
    float* __restrict__ A, float* __restrict__ Cstk, float* __restrict__ out)
{
  const int slab = blockIdx.x;          // 16 rows
  const int b = blockIdx.y;
  const double* Sb = S + (size_t)b * NN * NN;
  float* Ab = A + (size_t)b * NN * NN;
  const int tid = threadIdx.x;
  const int w = tid >> 6, lane = tid & 63;
  __shared__ double P[8][NN];           // 16 KB exclusive column prefixes
  __shared__ double diag[NN];
  {
    const double* ax = aux + (size_t)b * 8 * NN + tid;
    double run = 0.0;
    #pragma unroll
    for (int u = 0; u < 8; u++) { P[u][tid] = run; run += ax[(size_t)u * NN]; }
  }
  __syncthreads();
  diag[tid] = Sb[(size_t)tid * NN + tid] + P[tid >> 5][tid];
  __syncthreads();
  #pragma unroll
  for (int t = 0; t < 4; t++) {
    const int n = slab * 16 + w * 4 + t;
    const double snn = (n > 0) ? diag[n-1] : 0.0;
    const double* srow = Sb + (size_t)(n > 0 ? n-1 : 0) * NN;
    const double* Pr   = P[(n > 0 ? n-1 : 0) >> 5];
    #pragma unroll
    for (int c = 0; c < 4; c++) {
      const int jx = c * 64 + lane;
      float ds = INF;
      if (jx >= n) {
        const double sv = (n > 0) ? (srow[jx] + Pr[jx]) : 0.0;
        ds = (float)(diag[jx] - 2.0 * sv + snn);
      }
      if (jx < NN - 1) Ab[(size_t)n * NN + jx + 1] = ds;
      else             Cstk[(size_t)b * 32 * NN + n] = ds;   // Ds[n][N-1]
      if (jx == 0)     Ab[(size_t)n * NN + 0] = INF;
    }
  }
  if (slab == 0) out[b * NN + tid] = (tid == NN - 1) ? 1.0f : 0.0f;
}

// ---------------- full chain C_1..C_29, pure-A, row-PAIR sharing ---------------
// C_k = A (min-plus) C_{k-1}, 8-slot C ring in LDS. Each thread serves TWO
// adjacent rows (2p, 2p+1) from ONE C float4 read. Rows' cols <= row are INF
// in A's memory (ds_mat writes them), so the min set per row is unchanged ->
// bit-identical output. 128 pairs x 8 q-lanes; pair p = w + 16u balances
// waves; reduce over q via shfl_xor(1,2,4).
constexpr int CSTR = 260;    // ring stride: 16B-aligned, breaks pow2 banks
constexpr int RING = 8;      // ring depth (power of 2)

__global__ __launch_bounds__(1024) void chain_full(
    const float* __restrict__ A, float* __restrict__ Cstk)
{
  const int b = blockIdx.x;
  const int tid = threadIdx.x;
  const int lane = tid & 63, w = tid >> 6;   // 16 waves
  const int u = lane >> 3;                   // 0..7 group within wave
  const int qq = lane & 7;                   // 0..7 within pair
  const int p = w + 16 * u;                  // pair 0..127, balanced over waves
  const int n0 = 2 * p, n1 = 2 * p + 1;
  __shared__ __align__(16) float cs[RING * CSTR];    // 8.3 KB
  float* Ck = Cstk + (size_t)b * 32 * NN;
  const size_t mb = (size_t)b * NN * NN;

  const int jj0 = (n0 + 1) & ~3;       // aligned start; covers both rows
  const int La  = NN - jj0;            // floats from jj0 to end of row

  // ---- prefetch both rows' quarters into registers (masked, static idx) ------
  float4 a0[8], a1[8];
  {
    const float* r0 = A + mb + (size_t)n0 * NN + jj0;
    const float* r1 = A + mb + (size_t)n1 * NN + jj0;
    #pragma unroll
    for (int i = 0; i < 8; i++) {
      const int f = 4 * qq + 32 * i;
      if (f < La) { a0[i] = *(const float4*)(r0 + f); a1[i] = *(const float4*)(r1 + f); }
      else        { a0[i] = make_float4(INF, INF, INF, INF); a1[i] = a0[i]; }
    }
  }

  if (tid < NN) cs[tid] = Ck[tid];     // ring slot 0 = C0
  __syncthreads();

  for (int t = 0; t < 29; t++) {       // stage t: C_{t+1} = A (x) C_t
    float m0 = INF, m1 = INF;
    const float* cb = cs + (t & (RING-1)) * CSTR + jj0 + 4 * qq;
    #pragma unroll
    for (int i = 0; i < 8; i++) {
      const int f = 4 * qq + 32 * i;
      if (f < La) {
        const float4 c = *(const float4*)(cb + 32 * i);
        const float4 x = a0[i], y = a1[i];
        m0 = fminf(m0, fminf(fminf(x.x + c.x, x.y + c.y),
                             fminf(x.z + c.z, x.w + c.w)));
        m1 = fminf(m1, fminf(fminf(y.x + c.x, y.y + c.y),
                             fminf(y.z + c.z, y.w + c.w)));
      }
    }
    m0 = fminf(m0, __shfl_xor(m0, 1));
    m0 = fminf(m0, __shfl_xor(m0, 2));
    m0 = fminf(m0, __shfl_xor(m0, 4));
    m1 = fminf(m1, __shfl_xor(m1, 1));
    m1 = fminf(m1, __shfl_xor(m1, 2));
    m1 = fminf(m1, __shfl_xor(m1, 4));
    m0 = fminf(m0, INF);
    m1 = fminf(m1, INF);
    if (qq == 0) {
      cs[((t + 1) & (RING-1)) * CSTR + n0] = m0;
      cs[((t + 1) & (RING-1)) * CSTR + n1] = m1;
      Ck[(t + 1) * NN + n0] = m0;
      Ck[(t + 1) * NN + n1] = m1;
    }
    __syncthreads();
  }
}

// ---------------- fused softmax: row sums (LDS) + column accumulation ----------
__global__ __launch_bounds__(256) void sm_fused(
    const float* __restrict__ A, const float* __restrict__ Cstk,
    float* __restrict__ out)
{
  const int k = blockIdx.x + 1;        // 1..29
  const int b = blockIdx.y;
  const int limit = NN - k;
  const int tid = threadIdx.x;
  const float* Ab  = A + (size_t)b * NN * NN;
  const float* Ckb = Cstk + (size_t)b * 32 * NN;
  __shared__ __align__(16) float cprev[NN];   // C_{k-1}
  __shared__ float ck[NN];                    // C_k
  __shared__ float ivh[NN];                   // 1/s per row
  cprev[tid] = Ckb[(k - 1) * NN + tid];
  ck[tid]    = Ckb[k * NN + tid];
  __syncthreads();
  const int r = tid >> 2, q = tid & 3;
  #pragma unroll
  for (int rg = 0; rg < 4; rg++) {
    const int n = rg * 64 + r;
    const float m = ck[n];
    const float* Ar = Ab + (size_t)n * NN + q * 64;
    float s = 0.f;
    if (q * 64 + 63 > n) {              // chunk has some jj > n
      #pragma unroll 4
      for (int i = 0; i < 16; i++) {
        const float4 a = *(const float4*)(Ar + i * 4);
        const int jj = q * 64 + i * 4;
        const float4 c = *(const float4*)&cprev[jj];
        s += (jj + 0 <= limit) ? __expf(m - a.x - c.x) : 0.f;
        s += (jj + 1 <= limit) ? __expf(m - a.y - c.y) : 0.f;
        s += (jj + 2 <= limit) ? __expf(m - a.z - c.z) : 0.f;
        s += (jj + 3 <= limit) ? __expf(m - a.w - c.w) : 0.f;
      }
    }
    s += __shfl_xor(s, 1);
    s += __shfl_xor(s, 2);
    if (q == 0) ivh[n] = 1.0f / s;
  }
  __syncthreads();
  const int j = tid;
  if (j < limit) {
    const float cj = cprev[j + 1];
    const int nmax = (j < limit - 1) ? j : limit - 1;
    float a = 0.0f;
    #pragma unroll 4
    for (int nr = 0; nr <= nmax; nr++)
      a += __expf(ck[nr] - Ab[(size_t)nr * NN + j + 1] - cj) * ivh[nr];
    int kmaxj = NN - 1 - j; if (kmaxj > KMAX - 1) kmaxj = KMAX - 1;
    const float cnt = (float)((j + 1) * kmaxj);
    atomicAdd(&out[b * NN + j], a / cnt);
  }
}

extern "C" void kernel_launch(void* const* d_in, const int* in_sizes, int n_in,
                              void* d_out, int out_size, void* d_ws, size_t ws_size,
                              hipStream_t stream) {
  const float* x  = (const float*)d_in[0];
  const float* W0 = (const float*)d_in[1];
  const float* b0 = (const float*)d_in[2];
  const float* W1 = (const float*)d_in[3];
  const float* b1 = (const float*)d_in[4];
  float* out = (float*)d_out;

  // ws layout (max 7 MiB + 128 KiB used; ws proven >= 8 MiB):
  //  region        lifetime
  //  h    [0,2M)   gemm1 W -> gemm2 R
  //  S    [0,4M)   scan_slab W (h dead) -> ds_mat R    (slab-local scans)
  //  D    [4M,6M)  corr_dist W -> scan_slab R
  //  A    [4M,6M)  ds_mat W (D dead) -> chain/sm R
  //  z    [6M,7M)  gemm2 W -> corr_dist R
  //  Cstk [6M,6.25M) ds_mat W (z dead) -> chain RW -> sm R
  //  aux  [7M,7M+128K) scan_slab W -> ds_mat R
  char* base = (char*)d_ws;
  float*  h    = (float*)(base);
  double* S    = (double*)(base);
  float*  D    = (float*)(base + (4u << 20));
  float*  A    = (float*)(base + (4u << 20));
  float*  z    = (float*)(base + (6u << 20));
  float*  Cstk = (float*)(base + (6u << 20));
  double* aux  = (double*)(base + (7u << 20));

  gemm_bias_act<<<dim3(F1/64, ROWS/64), 256, 0, stream>>>(x, W0, b0, h, ROWS, F1, F0, 1);
  gemm_bias_act<<<dim3(F2/64, ROWS/64), 256, 0, stream>>>(h, W1, b1, z, ROWS, F2, F1, 0);
  corr_dist<<<dim3(NN/64, NN/64, NB), 256, 0, stream>>>(z, D);
  scan_slab<<<dim3(NB*8), 256, 0, stream>>>(D, S, aux);
  ds_mat<<<dim3(16, NB), 256, 0, stream>>>(S, aux, A, Cstk, out);
  chain_full<<<dim3(NB), 1024, 0, stream>>>(A, Cstk);
  sm_fused<<<dim3(KMAX-1, NB), 256, 0, stream>>>(A, Cstk, out);
}

// Round 14
// 186.030 us; speedup vs baseline: 1.0545x; 1.0545x over previous
//
#include <hip/hip_runtime.h>

constexpr int NB    = 8;     // batches
constexpr int NN    = 256;   // sequence length
constexpr int F0    = 512;
constexpr int F1    = 256;
constexpr int F2    = 128;
constexpr int ROWS  = NB * NN;   // 2048
constexpr int KMAX  = 30;
constexpr float INF = 1e30f;

// ---------------- fp32 GEMM: C = act(A @ B + bias), 64x32 tile, BK=16 ----------
// NOTE: 64x32 (256 blocks for gemm1) beats 64x64 (128 blocks): gemm1 runs on
// cold HBM right after the harness's 268MB poison fill and is latency-bound --
// block count, not arithmetic intensity, sets its speed (R12: 64x64 = 39.9us,
// Occupancy 4.8%).
__global__ __launch_bounds__(256) void gemm_bias_act(
    const float* __restrict__ A, const float* __restrict__ B,
    const float* __restrict__ bias, float* __restrict__ C,
    int M, int Ncols, int K, int relu)
{
  __shared__ float As[16][64];   // [k][m]
  __shared__ float Bs[16][32];   // [k][n]
  const int tid = threadIdx.x;
  const int tx = tid & 15;       // col group  (2 cols)
  const int ty = tid >> 4;       // row group  (4 rows)
  const int rowBase = blockIdx.y * 64;
  const int colBase = blockIdx.x * 32;
  float acc[4][2] = {};
  for (int k0 = 0; k0 < K; k0 += 16) {
    {
      const int r  = tid >> 2;
      const int kq = (tid & 3) << 2;
      const float4 av = *(const float4*)(A + (size_t)(rowBase + r) * K + (k0 + kq));
      As[kq+0][r] = av.x; As[kq+1][r] = av.y; As[kq+2][r] = av.z; As[kq+3][r] = av.w;
      const int kr = tid >> 4;
      const int c2 = (tid & 15) << 1;
      const float2 bv = *(const float2*)(B + (size_t)(k0 + kr) * Ncols + (colBase + c2));
      Bs[kr][c2+0] = bv.x; Bs[kr][c2+1] = bv.y;
    }
    __syncthreads();
    #pragma unroll
    for (int kk = 0; kk < 16; kk++) {
      const float4 a = *(const float4*)&As[kk][ty*4];
      const float b0v = Bs[kk][tx*2+0];
      const float b1v = Bs[kk][tx*2+1];
      acc[0][0] += a.x*b0v; acc[0][1] += a.x*b1v;
      acc[1][0] += a.y*b0v; acc[1][1] += a.y*b1v;
      acc[2][0] += a.z*b0v; acc[2][1] += a.z*b1v;
      acc[3][0] += a.w*b0v; acc[3][1] += a.w*b1v;
    }
    __syncthreads();
  }
  #pragma unroll
  for (int i = 0; i < 4; i++) {
    const int rr = rowBase + ty*4 + i;
    #pragma unroll
    for (int j = 0; j < 2; j++) {
      const int cc = colBase + tx*2 + j;
      float v = acc[i][j] + bias[cc];
      if (relu) v = fmaxf(v, 0.0f);
      C[(size_t)rr * Ncols + cc] = v;
    }
  }
}

// ---------------- D[b,n,m] = 0.5*(1 - (z_n.z_m)/sqrt(max(|z_n|^2|z_m|^2,1e-8)))
// Row/col norms accumulated in registers from the same LDS fragments.
__global__ __launch_bounds__(256) void corr_dist(
    const float* __restrict__ z, float* __restrict__ D)
{
  const int b = blockIdx.z;
  const float* zb = z + (size_t)b * NN * F2;
  __shared__ float As[16][64];  // [k][row]
  __shared__ float Bs[16][64];  // [k][col]
  const int tid = threadIdx.x;
  const int tx = tid & 15;
  const int ty = tid >> 4;
  const int rowBase = blockIdx.y * 64;
  const int colBase = blockIdx.x * 64;
  float acc[4][4] = {};
  float nsr[4] = {}, nsc[4] = {};
  for (int k0 = 0; k0 < F2; k0 += 16) {
    {
      const int r  = tid >> 2;
      const int kq = (tid & 3) << 2;
      const float4 av = *(const float4*)(zb + (size_t)(rowBase + r) * F2 + (k0 + kq));
      As[kq+0][r] = av.x; As[kq+1][r] = av.y; As[kq+2][r] = av.z; As[kq+3][r] = av.w;
      const float4 bv = *(const float4*)(zb + (size_t)(colBase + r) * F2 + (k0 + kq));
      Bs[kq+0][r] = bv.x; Bs[kq+1][r] = bv.y; Bs[kq+2][r] = bv.z; Bs[kq+3][r] = bv.w;
    }
    __syncthreads();
    #pragma unroll
    for (int kk = 0; kk < 16; kk++) {
      const float4 a = *(const float4*)&As[kk][ty*4];
      const float4 bq = *(const float4*)&Bs[kk][tx*4];
      const float ar[4] = {a.x, a.y, a.z, a.w};
      const float br[4] = {bq.x, bq.y, bq.z, bq.w};
      #pragma unroll
      for (int i = 0; i < 4; i++) { nsr[i] += ar[i]*ar[i]; nsc[i] += br[i]*br[i]; }
      #pragma unroll
      for (int i = 0; i < 4; i++)
        #pragma unroll
        for (int j = 0; j < 4; j++)
          acc[i][j] += ar[i] * br[j];
    }
    __syncthreads();
  }
  float* Db = D + (size_t)b * NN * NN;
  #pragma unroll
  for (int i = 0; i < 4; i++) {
    const int rr = rowBase + ty*4 + i;
    #pragma unroll
    for (int j = 0; j < 4; j++) {
      const int cc = colBase + tx*4 + j;
      const float denom = sqrtf(fmaxf(nsr[i] * nsc[j], 1e-8f));
      Db[(size_t)rr * NN + cc] = 0.5f * (1.0f - acc[i][j] / denom);
    }
  }
}

// ---------------- fused row scan + slab column scan ----------------------------
// Block = (batch, 32-row slab): row-scan 32 rows into a 64 KB LDS slab, then
// column-scan the slab in place; emit S (slab-local) + aux (slab totals).
__global__ __launch_bounds__(256) void scan_slab(
    const float* __restrict__ D, double* __restrict__ S, double* __restrict__ aux)
{
  const int s = blockIdx.x & 7;
  const int b = blockIdx.x >> 3;
  const int tid = threadIdx.x;
  const int wave = tid >> 6, lane = tid & 63;
  __shared__ double sd[32][NN];    // 64 KB
  for (int t = 0; t < 8; t++) {
    const int rl = wave * 8 + t;
    const float4 dv = *(const float4*)(D + (size_t)(b * NN + s * 32 + rl) * NN + lane * 4);
    double d0 = dv.x, d1 = dv.y, d2 = dv.z, d3 = dv.w;
    double p0 = d0, p1 = p0 + d1, p2 = p1 + d2, p3 = p2 + d3;
    double tt = p3;
    #pragma unroll
    for (int d = 1; d < 64; d <<= 1) {
      double u = __shfl_up(tt, d);
      if (lane >= d) tt += u;
    }
    const double off = tt - p3;
    sd[rl][lane*4+0] = off + p0; sd[rl][lane*4+1] = off + p1;
    sd[rl][lane*4+2] = off + p2; sd[rl][lane*4+3] = off + p3;
  }
  __syncthreads();
  const int j = tid;
  double* Sp = S + (size_t)b * NN * NN + (size_t)(s * 32) * NN + j;
  double sum = 0.0;
  for (int r = 0; r < 32; r += 8) {
    double v0 = sd[r+0][j], v1 = sd[r+1][j], v2 = sd[r+2][j], v3 = sd[r+3][j];
    double v4 = sd[r+4][j], v5 = sd[r+5][j], v6 = sd[r+6][j], v7 = sd[r+7][j];
    v0 += sum; v1 += v0; v2 += v1; v3 += v2; v4 += v3; v5 += v4; v6 += v5; v7 += v6;
    Sp[(size_t)(r+0)*NN] = v0; Sp[(size_t)(r+1)*NN] = v1;
    Sp[(size_t)(r+2)*NN] = v2; Sp[(size_t)(r+3)*NN] = v3;
    Sp[(size_t)(r+4)*NN] = v4; Sp[(size_t)(r+5)*NN] = v5;
    Sp[(size_t)(r+6)*NN] = v6; Sp[(size_t)(r+7)*NN] = v7;
    sum = v7;
  }
  aux[((size_t)b * 8 + s) * NN + j] = sum;
}

// ---------------- Ds -> A (shifted), C0 -> Cstk[0], out init -------------------
// S holds slab-local scans; cross-slab column offsets P (exclusive prefix of
// aux) are built in LDS and added on the fly: S_full[r][j] = S[r][j]+P[r>>5][j].
__global__ __launch_bounds__(256) void ds_mat(
    const double* __restrict__ S, const double* __restrict__ aux,
    float* __restrict__ A, float* __restrict__ Cstk, float* __restrict__ out)
{
  const int slab = blockIdx.x;          // 16 rows
  const int b = blockIdx.y;
  const double* Sb = S + (size_t)b * NN * NN;
  float* Ab = A + (size_t)b * NN * NN;
  const int tid = threadIdx.x;
  const int w = tid >> 6, lane = tid & 63;
  __shared__ double P[8][NN];           // 16 KB exclusive column prefixes
  __shared__ double diag[NN];
  {
    const double* ax = aux + (size_t)b * 8 * NN + tid;
    double run = 0.0;
    #pragma unroll
    for (int u = 0; u < 8; u++) { P[u][tid] = run; run += ax[(size_t)u * NN]; }
  }
  __syncthreads();
  diag[tid] = Sb[(size_t)tid * NN + tid] + P[tid >> 5][tid];
  __syncthreads();
  #pragma unroll
  for (int t = 0; t < 4; t++) {
    const int n = slab * 16 + w * 4 + t;
    const double snn = (n > 0) ? diag[n-1] : 0.0;
    const double* srow = Sb + (size_t)(n > 0 ? n-1 : 0) * NN;
    const double* Pr   = P[(n > 0 ? n-1 : 0) >> 5];
    #pragma unroll
    for (int c = 0; c < 4; c++) {
      const int jx = c * 64 + lane;
      float ds = INF;
      if (jx >= n) {
        const double sv = (n > 0) ? (srow[jx] + Pr[jx]) : 0.0;
        ds = (float)(diag[jx] - 2.0 * sv + snn);
      }
      if (jx < NN - 1) Ab[(size_t)n * NN + jx + 1] = ds;
      else             Cstk[(size_t)b * 32 * NN + n] = ds;   // Ds[n][N-1]
      if (jx == 0)     Ab[(size_t)n * NN + 0] = INF;
    }
  }
  if (slab == 0) out[b * NN + tid] = (tid == NN - 1) ? 1.0f : 0.0f;
}

// ---------------- full chain C_1..C_29, pure-A: 29 stages, 1 block/batch -------
// C_k = A (min-plus) C_{k-1}, 8-slot C ring in LDS. Per thread: its quarter of
// A row n (16 masked float4, static idx) in VGPRs; cols < n+1 are INF in
// memory and never win the min. (R7-verified best: 186.2 us total. Chain
// micro-variants -- balanced wave mapping, row-pair C-sharing -- measured
// neutral: the stage loop is latency/barrier-bound, not LDS-throughput-bound.)
constexpr int CSTR = 260;    // ring stride: 16B-aligned, breaks pow2 banks
constexpr int RING = 8;      // ring depth (power of 2)

__global__ __launch_bounds__(1024) void chain_full(
    const float* __restrict__ A, float* __restrict__ Cstk)
{
  const int b = blockIdx.x;
  const int tid = threadIdx.x;
  const int n = tid >> 2, q = tid & 3;
  __shared__ __align__(16) float cs[RING * CSTR];    // 8.3 KB
  float* Ck = Cstk + (size_t)b * 32 * NN;
  const size_t mb = (size_t)b * NN * NN;

  const int jj0 = (n + 1) & ~3;        // first float4-aligned col >= n+1
  const int La  = NN - jj0;            // floats from jj0 to end of row

  // ---- prefetch this thread's A-row quarter into registers (masked) ----------
  float4 areg[16];
  {
    const float* ar = A + mb + (size_t)n * NN + jj0;
    #pragma unroll
    for (int fi = 0; fi < 16; fi++) {
      const int f = 4 * q + 16 * fi;
      if (f < La) areg[fi] = *(const float4*)(ar + f);
      else        areg[fi] = make_float4(INF, INF, INF, INF);
    }
  }

  if (tid < NN) cs[tid] = Ck[tid];     // ring slot 0 = C0
  __syncthreads();

  for (int t = 0; t < 29; t++) {       // stage t: C_{t+1} = A (x) C_t
    float m = INF;
    const float* cb = cs + (t & (RING-1)) * CSTR + jj0 + 4 * q;
    #pragma unroll
    for (int fi = 0; fi < 16; fi++) {
      const int f = 4 * q + 16 * fi;
      if (f < La) {
        const float4 a = areg[fi];
        const float4 c = *(const float4*)(cb + 16 * fi);
        m = fminf(m, fminf(fminf(a.x + c.x, a.y + c.y),
                           fminf(a.z + c.z, a.w + c.w)));
      }
    }
    m = fminf(m, __shfl_xor(m, 1));
    m = fminf(m, __shfl_xor(m, 2));
    m = fminf(m, INF);
    if (q == 0) {
      cs[((t + 1) & (RING-1)) * CSTR + n] = m;
      Ck[(t + 1) * NN + n] = m;
    }
    __syncthreads();
  }
}

// ---------------- fused softmax: row sums (LDS) + column accumulation ----------
__global__ __launch_bounds__(256) void sm_fused(
    const float* __restrict__ A, const float* __restrict__ Cstk,
    float* __restrict__ out)
{
  const int k = blockIdx.x + 1;        // 1..29
  const int b = blockIdx.y;
  const int limit = NN - k;
  const int tid = threadIdx.x;
  const float* Ab  = A + (size_t)b * NN * NN;
  const float* Ckb = Cstk + (size_t)b * 32 * NN;
  __shared__ __align__(16) float cprev[NN];   // C_{k-1}
  __shared__ float ck[NN];                    // C_k
  __shared__ float ivh[NN];                   // 1/s per row
  cprev[tid] = Ckb[(k - 1) * NN + tid];
  ck[tid]    = Ckb[k * NN + tid];
  __syncthreads();
  const int r = tid >> 2, q = tid & 3;
  #pragma unroll
  for (int rg = 0; rg < 4; rg++) {
    const int n = rg * 64 + r;
    const float m = ck[n];
    const float* Ar = Ab + (size_t)n * NN + q * 64;
    float s = 0.f;
    if (q * 64 + 63 > n) {              // chunk has some jj > n
      #pragma unroll 4
      for (int i = 0; i < 16; i++) {
        const float4 a = *(const float4*)(Ar + i * 4);
        const int jj = q * 64 + i * 4;
        const float4 c = *(const float4*)&cprev[jj];
        s += (jj + 0 <= limit) ? __expf(m - a.x - c.x) : 0.f;
        s += (jj + 1 <= limit) ? __expf(m - a.y - c.y) : 0.f;
        s += (jj + 2 <= limit) ? __expf(m - a.z - c.z) : 0.f;
        s += (jj + 3 <= limit) ? __expf(m - a.w - c.w) : 0.f;
      }
    }
    s += __shfl_xor(s, 1);
    s += __shfl_xor(s, 2);
    if (q == 0) ivh[n] = 1.0f / s;
  }
  __syncthreads();
  const int j = tid;
  if (j < limit) {
    const float cj = cprev[j + 1];
    const int nmax = (j < limit - 1) ? j : limit - 1;
    float a = 0.0f;
    #pragma unroll 4
    for (int nr = 0; nr <= nmax; nr++)
      a += __expf(ck[nr] - Ab[(size_t)nr * NN + j + 1] - cj) * ivh[nr];
    int kmaxj = NN - 1 - j; if (kmaxj > KMAX - 1) kmaxj = KMAX - 1;
    const float cnt = (float)((j + 1) * kmaxj);
    atomicAdd(&out[b * NN + j], a / cnt);
  }
}

extern "C" void kernel_launch(void* const* d_in, const int* in_sizes, int n_in,
                              void* d_out, int out_size, void* d_ws, size_t ws_size,
                              hipStream_t stream) {
  const float* x  = (const float*)d_in[0];
  const float* W0 = (const float*)d_in[1];
  const float* b0 = (const float*)d_in[2];
  const float* W1 = (const float*)d_in[3];
  const float* b1 = (const float*)d_in[4];
  float* out = (float*)d_out;

  // ws layout (max 7 MiB + 128 KiB used; ws proven >= 8 MiB):
  //  region        lifetime
  //  h    [0,2M)   gemm1 W -> gemm2 R
  //  S    [0,4M)   scan_slab W (h dead) -> ds_mat R    (slab-local scans)
  //  D    [4M,6M)  corr_dist W -> scan_slab R
  //  A    [4M,6M)  ds_mat W (D dead) -> chain/sm R
  //  z    [6M,7M)  gemm2 W -> corr_dist R
  //  Cstk [6M,6.25M) ds_mat W (z dead) -> chain RW -> sm R
  //  aux  [7M,7M+128K) scan_slab W -> ds_mat R
  char* base = (char*)d_ws;
  float*  h    = (float*)(base);
  double* S    = (double*)(base);
  float*  D    = (float*)(base + (4u << 20));
  float*  A    = (float*)(base + (4u << 20));
  float*  z    = (float*)(base + (6u << 20));
  float*  Cstk = (float*)(base + (6u << 20));
  double* aux  = (double*)(base + (7u << 20));

  gemm_bias_act<<<dim3(F1/32, ROWS/64), 256, 0, stream>>>(x, W0, b0, h, ROWS, F1, F0, 1);
  gemm_bias_act<<<dim3(F2/32, ROWS/64), 256, 0, stream>>>(h, W1, b1, z, ROWS, F2, F1, 0);
  corr_dist<<<dim3(NN/64, NN/64, NB), 256, 0, stream>>>(z, D);
  scan_slab<<<dim3(NB*8), 256, 0, stream>>>(D, S, aux);
  ds_mat<<<dim3(16, NB), 256, 0, stream>>>(S, aux, A, Cstk, out);
  chain_full<<<dim3(NB), 1024, 0, stream>>>(A, Cstk);
  sm_fused<<<dim3(KMAX-1, NB), 256, 0, stream>>>(A, Cstk, out);
}